// Round 1
// baseline (244.053 us; speedup 1.0000x reference)
//
#include <hip/hip_runtime.h>

#define D 128
#define D4 32   // floats4 per row

// ---------------- CSR build ----------------

__global__ void count_kernel(const int* __restrict__ dst, int* __restrict__ cnt, int E) {
    int e = blockIdx.x * blockDim.x + threadIdx.x;
    if (e < E) atomicAdd(&cnt[dst[e]], 1);
}

// Per-node region allocation: wave-level prefix sum + one atomic per wave.
// Regions need not be globally ordered, only contiguous per node.
__global__ void alloc_kernel(const int* __restrict__ cnt, int* __restrict__ start,
                             int* __restrict__ cur, int* __restrict__ total, int n) {
    int i = blockIdx.x * blockDim.x + threadIdx.x;
    int lane = threadIdx.x & 63;
    int c = (i < n) ? cnt[i] : 0;
    int inc = c;
    #pragma unroll
    for (int s = 1; s < 64; s <<= 1) {
        int u = __shfl_up(inc, (unsigned)s);
        if (lane >= s) inc += u;
    }
    int base = 0;
    if (lane == 63) base = atomicAdd(total, inc);
    base = __shfl(base, 63);
    if (i < n) { int st = base + inc - c; start[i] = st; cur[i] = st; }
}

__global__ void fill_kernel(const int* __restrict__ src, const int* __restrict__ dst,
                            int* __restrict__ cur, int* __restrict__ bucket, int E) {
    int e = blockIdx.x * blockDim.x + threadIdx.x;
    if (e < E) {
        int p = atomicAdd(&cur[dst[e]], 1);
        bucket[p] = src[e];
    }
}

// ---------------- gather: z = x + segment_sum(x[src], dst) ----------------
// half-wave (32 lanes, float4 each) per node; x rows are 512B contiguous reads.
__global__ void gather_kernel(const float4* __restrict__ x4, const int* __restrict__ start,
                              const int* __restrict__ cnt, const int* __restrict__ bucket,
                              float4* __restrict__ z4, int n) {
    int node = blockIdx.x * 8 + (threadIdx.x >> 5);
    int lane = threadIdx.x & 31;
    if (node >= n) return;
    int e0 = start[node];
    int e1 = e0 + cnt[node];
    float ax = 0.f, ay = 0.f, az = 0.f, aw = 0.f;
    for (int e = e0; e < e1; ++e) {
        int s = bucket[e];
        float4 v = x4[(size_t)s * D4 + lane];
        ax += v.x; ay += v.y; az += v.z; aw += v.w;
    }
    float4 xv = x4[(size_t)node * D4 + lane];
    float4 o;
    o.x = ax + xv.x; o.y = ay + xv.y; o.z = az + xv.z; o.w = aw + xv.w;
    z4[(size_t)node * D4 + lane] = o;
}

// ---------------- fp32 GEMM: out[n,128] = act(in[n,128] @ W[128,128] + bias) ----------------
// W (64KB) + 32-row input tile (16KB) in LDS; thread computes 4 rows x 4 cols.
template<bool RELU>
__global__ __launch_bounds__(256)
void gemm_kernel(const float4* __restrict__ in4, const float4* __restrict__ W4,
                 const float* __restrict__ bias, float4* __restrict__ out4, int n) {
    __shared__ float4 Ws[128 * 32];
    __shared__ float4 zs[32][32];
    int t = threadIdx.x;
    int tx = t & 31, ty = t >> 5;
    #pragma unroll
    for (int i = 0; i < 16; ++i) Ws[t + i * 256] = W4[t + i * 256];
    int rbase = blockIdx.x * 32;
    #pragma unroll
    for (int i = 0; i < 4; ++i) {
        int idx = t + i * 256;
        int rr = idx >> 5, cc = idx & 31;
        int gr = rbase + rr;
        float4 v = make_float4(0.f, 0.f, 0.f, 0.f);
        if (gr < n) v = in4[(size_t)gr * D4 + cc];
        zs[rr][cc] = v;
    }
    __syncthreads();
    float4 acc[4];
    #pragma unroll
    for (int i = 0; i < 4; ++i) acc[i] = make_float4(0.f, 0.f, 0.f, 0.f);
    #pragma unroll 4
    for (int kk = 0; kk < 32; ++kk) {
        float4 b0 = Ws[(kk * 4 + 0) * 32 + tx];
        float4 b1v = Ws[(kk * 4 + 1) * 32 + tx];
        float4 b2v = Ws[(kk * 4 + 2) * 32 + tx];
        float4 b3v = Ws[(kk * 4 + 3) * 32 + tx];
        #pragma unroll
        for (int i = 0; i < 4; ++i) {
            float4 a = zs[ty * 4 + i][kk];
            acc[i].x += a.x * b0.x + a.y * b1v.x + a.z * b2v.x + a.w * b3v.x;
            acc[i].y += a.x * b0.y + a.y * b1v.y + a.z * b2v.y + a.w * b3v.y;
            acc[i].z += a.x * b0.z + a.y * b1v.z + a.z * b2v.z + a.w * b3v.z;
            acc[i].w += a.x * b0.w + a.y * b1v.w + a.z * b2v.w + a.w * b3v.w;
        }
    }
    float4 bb = ((const float4*)bias)[tx];
    #pragma unroll
    for (int i = 0; i < 4; ++i) {
        int gr = rbase + ty * 4 + i;
        if (gr < n) {
            float4 o;
            o.x = acc[i].x + bb.x; o.y = acc[i].y + bb.y;
            o.z = acc[i].z + bb.z; o.w = acc[i].w + bb.w;
            if (RELU) {
                o.x = fmaxf(o.x, 0.f); o.y = fmaxf(o.y, 0.f);
                o.z = fmaxf(o.z, 0.f); o.w = fmaxf(o.w, 0.f);
            }
            out4[(size_t)gr * D4 + tx] = o;
        }
    }
}

// ---------------- BN stats: per-channel sum and sumsq ----------------
__global__ void stats_kernel(const float* __restrict__ h, float* __restrict__ stats, int n) {
    __shared__ float red[256];
    int c = threadIdx.x & 127;
    int half = threadIdx.x >> 7;
    float s = 0.f, q = 0.f;
    for (int r = blockIdx.x * 2 + half; r < n; r += gridDim.x * 2) {
        float v = h[(size_t)r * D + c];
        s += v; q += v * v;
    }
    red[threadIdx.x] = s; __syncthreads();
    if (half == 0) s += red[threadIdx.x + 128];
    __syncthreads();
    red[threadIdx.x] = q; __syncthreads();
    if (half == 0) {
        q += red[threadIdx.x + 128];
        atomicAdd(&stats[c], s);
        atomicAdd(&stats[128 + c], q);
    }
}

// ---------------- BN normalize + residual (in-place on d_out) ----------------
__global__ void bn_final(float4* __restrict__ out4, const float4* __restrict__ x4,
                         const float* __restrict__ stats, const float* __restrict__ gamma,
                         const float* __restrict__ beta, int n4, float invN) {
    int i = blockIdx.x * blockDim.x + threadIdx.x;
    if (i >= n4) return;
    int cc = i & 31;
    const float4* s4 = (const float4*)stats;
    float4 sum = s4[cc], sq = s4[32 + cc];
    float4 g = ((const float4*)gamma)[cc], b = ((const float4*)beta)[cc];
    float4 h = out4[i], xx = x4[i];
    float4 o;
    {
        float m = sum.x * invN, v = sq.x * invN - m * m, iv = rsqrtf(v + 1e-5f);
        o.x = (h.x - m) * iv * g.x + b.x + xx.x;
    }
    {
        float m = sum.y * invN, v = sq.y * invN - m * m, iv = rsqrtf(v + 1e-5f);
        o.y = (h.y - m) * iv * g.y + b.y + xx.y;
    }
    {
        float m = sum.z * invN, v = sq.z * invN - m * m, iv = rsqrtf(v + 1e-5f);
        o.z = (h.z - m) * iv * g.z + b.z + xx.z;
    }
    {
        float m = sum.w * invN, v = sq.w * invN - m * m, iv = rsqrtf(v + 1e-5f);
        o.w = (h.w - m) * iv * g.w + b.w + xx.w;
    }
    out4[i] = o;
}

extern "C" void kernel_launch(void* const* d_in, const int* in_sizes, int n_in,
                              void* d_out, int out_size, void* d_ws, size_t ws_size,
                              hipStream_t stream) {
    const float* x     = (const float*)d_in[0];
    const int*   ei    = (const int*)d_in[1];
    const float* W1    = (const float*)d_in[2];
    const float* b1    = (const float*)d_in[3];
    const float* W2    = (const float*)d_in[4];
    const float* b2    = (const float*)d_in[5];
    const float* gamma = (const float*)d_in[6];
    const float* beta  = (const float*)d_in[7];
    float* out = (float*)d_out;

    int N = in_sizes[0] / D;   // 50000
    int E = in_sizes[1] / 2;   // 600000
    const int* src = ei;
    const int* dst = ei + E;

    // workspace layout (ws base assumed 16B aligned)
    float* w    = (float*)d_ws;
    float* z    = w;                                  // N*D floats
    float* h1   = w + (size_t)N * D;                  // N*D floats
    float* stats = h1 + (size_t)N * D;                // 256 floats (16B aligned)
    int*   cnt  = (int*)(stats + 256);                // N ints
    int*   tot  = cnt + N;                            // 1 int
    int*   start = tot + 1;                           // N ints
    int*   cur  = start + N;                          // N ints
    int*   bucket = cur + N;                          // E ints

    // zero: stats(256f) + cnt(N) + tot(1) are contiguous
    hipMemsetAsync(stats, 0, (size_t)(256 + N + 1) * sizeof(int), stream);

    const int B = 256;
    count_kernel<<<(E + B - 1) / B, B, 0, stream>>>(dst, cnt, E);
    alloc_kernel<<<(N + B - 1) / B, B, 0, stream>>>(cnt, start, cur, tot, N);
    fill_kernel<<<(E + B - 1) / B, B, 0, stream>>>(src, dst, cur, bucket, E);
    gather_kernel<<<(N + 7) / 8, B, 0, stream>>>((const float4*)x, start, cnt, bucket,
                                                 (float4*)z, N);
    gemm_kernel<true><<<(N + 31) / 32, B, 0, stream>>>((const float4*)z, (const float4*)W1,
                                                       b1, (float4*)h1, N);
    gemm_kernel<false><<<(N + 31) / 32, B, 0, stream>>>((const float4*)h1, (const float4*)W2,
                                                        b2, (float4*)out, N);
    stats_kernel<<<256, 256, 0, stream>>>(out, stats, N);
    int n4 = N * D4;
    bn_final<<<(n4 + B - 1) / B, B, 0, stream>>>((float4*)out, (const float4*)x, stats,
                                                 gamma, beta, n4, 1.0f / (float)N);
}

// Round 2
// 214.943 us; speedup vs baseline: 1.1354x; 1.1354x over previous
//
#include <hip/hip_runtime.h>

#define D 128
#define D4 32   // float4 per row
#define D8 16   // ushort4 (8B) per bf16 row... actually 32 ushort4 per 128-elem row

typedef short s16x8 __attribute__((ext_vector_type(8)));
typedef float f32x4 __attribute__((ext_vector_type(4)));

__device__ __forceinline__ float bf2f(ushort h) {
    return __uint_as_float(((uint)h) << 16);
}
__device__ __forceinline__ ushort f2bf(float f) {
    uint u = __float_as_uint(f);
    u += 0x7fffu + ((u >> 16) & 1u);   // RNE
    return (ushort)(u >> 16);
}

// ---------------- CSR build ----------------

__global__ void count_kernel(const int* __restrict__ dst, int* __restrict__ cnt, int E) {
    int e = blockIdx.x * blockDim.x + threadIdx.x;
    if (e < E) atomicAdd(&cnt[dst[e]], 1);
}

__global__ void alloc_kernel(const int* __restrict__ cnt, int* __restrict__ start,
                             int* __restrict__ cur, int* __restrict__ total, int n) {
    int i = blockIdx.x * blockDim.x + threadIdx.x;
    int lane = threadIdx.x & 63;
    int c = (i < n) ? cnt[i] : 0;
    int inc = c;
    #pragma unroll
    for (int s = 1; s < 64; s <<= 1) {
        int u = __shfl_up(inc, (unsigned)s);
        if (lane >= s) inc += u;
    }
    int base = 0;
    if (lane == 63) base = atomicAdd(total, inc);
    base = __shfl(base, 63);
    if (i < n) { int st = base + inc - c; start[i] = st; cur[i] = st; }
}

__global__ void fill_kernel(const int* __restrict__ src, const int* __restrict__ dst,
                            int* __restrict__ cur, int* __restrict__ bucket, int E) {
    int e = blockIdx.x * blockDim.x + threadIdx.x;
    if (e < E) {
        int p = atomicAdd(&cur[dst[e]], 1);
        bucket[p] = src[e];
    }
}

// ---------------- x -> bf16 ----------------
__global__ void convert_x(const float4* __restrict__ x4, ushort4* __restrict__ xh4, int n4) {
    int i = blockIdx.x * blockDim.x + threadIdx.x;
    if (i >= n4) return;
    float4 v = x4[i];
    ushort4 h;
    h.x = f2bf(v.x); h.y = f2bf(v.y); h.z = f2bf(v.z); h.w = f2bf(v.w);
    xh4[i] = h;
}

// ---------------- W -> packed split-bf16 B-fragments ----------------
// Fragment layout for mfma_f32_16x16x32_bf16 B-operand:
// lane l, elem i (0..7) holds W[ks*32 + (l>>4)*8 + i][nf*16 + (l&15)]
// Packed index: ((ks*8+nf)*64 + lane)*8 + i,  ks=0..3, nf=0..7.
// wp layout: [m(W1/W2)][hi(16384) | lo(16384)] ushorts.
__global__ void pack_w(const float* __restrict__ W1, const float* __restrict__ W2,
                       ushort* __restrict__ wp) {
    int tid = blockIdx.x * blockDim.x + threadIdx.x;   // 0..4095
    if (tid >= 4096) return;
    int m = tid >> 11;
    int r = tid & 2047;
    int lane = r & 63;
    int nf = (r >> 6) & 7;
    int ks = r >> 9;
    const float* W = m ? W2 : W1;
    ushort* hi = wp + m * 32768;
    ushort* lo = hi + 16384;
    int k0 = ks * 32 + ((lane >> 4) << 3);
    int c = nf * 16 + (lane & 15);
    #pragma unroll
    for (int i = 0; i < 8; ++i) {
        float v = W[(k0 + i) * D + c];
        ushort h = f2bf(v);
        hi[r * 8 + i] = h;
        lo[r * 8 + i] = f2bf(v - bf2f(h));
    }
}

// ---------------- gather: z = x + segment_sum(x[src]) -> split bf16 ----------------
// half-wave (32 lanes, 8B/lane) per node; bf16 rows are 256B; 4x unroll for MLP.
__global__ void gather_kernel(const ushort4* __restrict__ xh4, const float4* __restrict__ x4,
                              const int* __restrict__ start, const int* __restrict__ cnt,
                              const int* __restrict__ bucket,
                              ushort4* __restrict__ zhi4, ushort4* __restrict__ zlo4, int n) {
    int node = blockIdx.x * 8 + (threadIdx.x >> 5);
    int lane = threadIdx.x & 31;
    if (node >= n) return;
    int e0 = start[node];
    int eend = e0 + cnt[node];
    float a0 = 0.f, a1 = 0.f, a2 = 0.f, a3 = 0.f;
    int e = e0;
    for (; e + 4 <= eend; e += 4) {
        int s0 = bucket[e], s1 = bucket[e + 1], s2 = bucket[e + 2], s3 = bucket[e + 3];
        ushort4 v0 = xh4[(size_t)s0 * 32 + lane];
        ushort4 v1 = xh4[(size_t)s1 * 32 + lane];
        ushort4 v2 = xh4[(size_t)s2 * 32 + lane];
        ushort4 v3 = xh4[(size_t)s3 * 32 + lane];
        a0 += bf2f(v0.x) + bf2f(v1.x) + bf2f(v2.x) + bf2f(v3.x);
        a1 += bf2f(v0.y) + bf2f(v1.y) + bf2f(v2.y) + bf2f(v3.y);
        a2 += bf2f(v0.z) + bf2f(v1.z) + bf2f(v2.z) + bf2f(v3.z);
        a3 += bf2f(v0.w) + bf2f(v1.w) + bf2f(v2.w) + bf2f(v3.w);
    }
    for (; e < eend; ++e) {
        int s = bucket[e];
        ushort4 v = xh4[(size_t)s * 32 + lane];
        a0 += bf2f(v.x); a1 += bf2f(v.y); a2 += bf2f(v.z); a3 += bf2f(v.w);
    }
    float4 xv = x4[(size_t)node * D4 + lane];
    float z0 = a0 + xv.x, z1 = a1 + xv.y, z2 = a2 + xv.z, z3 = a3 + xv.w;
    ushort4 hi, lo;
    hi.x = f2bf(z0); lo.x = f2bf(z0 - bf2f(hi.x));
    hi.y = f2bf(z1); lo.y = f2bf(z1 - bf2f(hi.y));
    hi.z = f2bf(z2); lo.z = f2bf(z2 - bf2f(hi.z));
    hi.w = f2bf(z3); lo.w = f2bf(z3 - bf2f(hi.w));
    zhi4[(size_t)node * 32 + lane] = hi;
    zlo4[(size_t)node * 32 + lane] = lo;
}

// ---------------- MFMA GEMM: C[16-row tile][128] = A[.][128] @ W + bias ----------------
// A split bf16 (hi/lo), W split bf16 packed fragments in LDS.
// acc = Ahi*Whi + Alo*Whi + Ahi*Wlo  (Alo*Wlo negligible)
template<bool RELU, bool SPLIT>
__global__ __launch_bounds__(256, 2)
void mfma_gemm(const ushort* __restrict__ Ahi, const ushort* __restrict__ Alo,
               const ushort* __restrict__ Whi, const ushort* __restrict__ Wlo,
               const float* __restrict__ bias,
               ushort* __restrict__ Ohi, ushort* __restrict__ Olo,
               float* __restrict__ Of, int nTiles) {
    __shared__ ushort Ws[2][16384];   // 64 KB: [0]=hi, [1]=lo
    {
        const float4* gH = (const float4*)Whi;
        const float4* gL = (const float4*)Wlo;
        float4* lH = (float4*)Ws[0];
        float4* lL = (float4*)Ws[1];
        for (int i = threadIdx.x; i < 2048; i += 256) { lH[i] = gH[i]; lL[i] = gL[i]; }
    }
    __syncthreads();
    int wave = threadIdx.x >> 6, lane = threadIdx.x & 63;
    int rsel = lane & 15;      // A row within tile / C col within frag
    int csel = lane >> 4;      // k-chunk / C row group
    for (int tile = blockIdx.x * 4 + wave; tile < nTiles; tile += gridDim.x * 4) {
        int row0 = tile * 16;
        const ushort* aH = Ahi + (size_t)(row0 + rsel) * D + csel * 8;
        const ushort* aL = Alo + (size_t)(row0 + rsel) * D + csel * 8;
        f32x4 acc[8];
        #pragma unroll
        for (int nf = 0; nf < 8; ++nf) acc[nf] = (f32x4){0.f, 0.f, 0.f, 0.f};
        #pragma unroll
        for (int ks = 0; ks < 4; ++ks) {
            s16x8 ahi = *(const s16x8*)(aH + ks * 32);
            s16x8 alo = *(const s16x8*)(aL + ks * 32);
            #pragma unroll
            for (int nf = 0; nf < 8; ++nf) {
                s16x8 bhi = *(const s16x8*)(&Ws[0][((ks * 8 + nf) * 64 + lane) * 8]);
                s16x8 blo = *(const s16x8*)(&Ws[1][((ks * 8 + nf) * 64 + lane) * 8]);
                acc[nf] = __builtin_amdgcn_mfma_f32_16x16x32_bf16(ahi, bhi, acc[nf], 0, 0, 0);
                acc[nf] = __builtin_amdgcn_mfma_f32_16x16x32_bf16(alo, bhi, acc[nf], 0, 0, 0);
                acc[nf] = __builtin_amdgcn_mfma_f32_16x16x32_bf16(ahi, blo, acc[nf], 0, 0, 0);
            }
        }
        int orow0 = row0 + csel * 4;
        #pragma unroll
        for (int nf = 0; nf < 8; ++nf) {
            int col = nf * 16 + rsel;
            float bb = bias[col];
            #pragma unroll
            for (int r = 0; r < 4; ++r) {
                float v = acc[nf][r] + bb;
                if (RELU) v = fmaxf(v, 0.f);
                size_t idx = (size_t)(orow0 + r) * D + col;
                if (SPLIT) {
                    ushort h = f2bf(v);
                    Ohi[idx] = h;
                    Olo[idx] = f2bf(v - bf2f(h));
                } else {
                    Of[idx] = v;
                }
            }
        }
    }
}

// ---------------- BN stats ----------------
__global__ void stats_kernel(const float* __restrict__ h, float* __restrict__ stats, int n) {
    __shared__ float red[256];
    int c = threadIdx.x & 127;
    int half = threadIdx.x >> 7;
    float s = 0.f, q = 0.f;
    for (int r = blockIdx.x * 2 + half; r < n; r += gridDim.x * 2) {
        float v = h[(size_t)r * D + c];
        s += v; q += v * v;
    }
    red[threadIdx.x] = s; __syncthreads();
    if (half == 0) s += red[threadIdx.x + 128];
    __syncthreads();
    red[threadIdx.x] = q; __syncthreads();
    if (half == 0) {
        q += red[threadIdx.x + 128];
        atomicAdd(&stats[c], s);
        atomicAdd(&stats[128 + c], q);
    }
}

// ---------------- BN normalize + residual ----------------
__global__ void bn_final(float4* __restrict__ out4, const float4* __restrict__ x4,
                         const float* __restrict__ stats, const float* __restrict__ gamma,
                         const float* __restrict__ beta, int n4, float invN) {
    int i = blockIdx.x * blockDim.x + threadIdx.x;
    if (i >= n4) return;
    int cc = i & 31;
    const float4* s4 = (const float4*)stats;
    float4 sum = s4[cc], sq = s4[32 + cc];
    float4 g = ((const float4*)gamma)[cc], b = ((const float4*)beta)[cc];
    float4 h = out4[i], xx = x4[i];
    float4 o;
    {
        float m = sum.x * invN, v = sq.x * invN - m * m, iv = rsqrtf(v + 1e-5f);
        o.x = (h.x - m) * iv * g.x + b.x + xx.x;
    }
    {
        float m = sum.y * invN, v = sq.y * invN - m * m, iv = rsqrtf(v + 1e-5f);
        o.y = (h.y - m) * iv * g.y + b.y + xx.y;
    }
    {
        float m = sum.z * invN, v = sq.z * invN - m * m, iv = rsqrtf(v + 1e-5f);
        o.z = (h.z - m) * iv * g.z + b.z + xx.z;
    }
    {
        float m = sum.w * invN, v = sq.w * invN - m * m, iv = rsqrtf(v + 1e-5f);
        o.w = (h.w - m) * iv * g.w + b.w + xx.w;
    }
    out4[i] = o;
}

extern "C" void kernel_launch(void* const* d_in, const int* in_sizes, int n_in,
                              void* d_out, int out_size, void* d_ws, size_t ws_size,
                              hipStream_t stream) {
    const float* x     = (const float*)d_in[0];
    const int*   ei    = (const int*)d_in[1];
    const float* W1    = (const float*)d_in[2];
    const float* b1    = (const float*)d_in[3];
    const float* W2    = (const float*)d_in[4];
    const float* b2    = (const float*)d_in[5];
    const float* gamma = (const float*)d_in[6];
    const float* beta  = (const float*)d_in[7];
    float* out = (float*)d_out;

    int N = in_sizes[0] / D;   // 50000
    int E = in_sizes[1] / 2;   // 600000
    const int* src = ei;
    const int* dst = ei + E;

    size_t NB = (size_t)N * D;
    // workspace layout
    ushort* zhi  = (ushort*)d_ws;          // NB
    ushort* zlo  = zhi + NB;               // NB
    ushort* h1hi = zlo + NB;               // NB  (aliased as xh before gemm1)
    ushort* h1lo = h1hi + NB;              // NB
    ushort* wp   = h1lo + NB;              // 4*16384
    float*  stats = (float*)(wp + 65536);  // 256
    int*    cnt  = (int*)(stats + 256);    // N
    int*    tot  = cnt + N;                // 1
    int*    startA = tot + 1;              // N
    int*    cur  = startA + N;             // N
    int*    bucket = cur + N;              // E
    ushort* xh   = h1hi;                   // alias: valid until gemm1

    hipMemsetAsync(stats, 0, (size_t)(256 + N + 1) * sizeof(int), stream);

    const int B = 256;
    int n4 = (int)(NB / 4);
    convert_x<<<(n4 + B - 1) / B, B, 0, stream>>>((const float4*)x, (ushort4*)xh, n4);
    pack_w<<<16, B, 0, stream>>>(W1, W2, wp);
    count_kernel<<<(E + B - 1) / B, B, 0, stream>>>(dst, cnt, E);
    alloc_kernel<<<(N + B - 1) / B, B, 0, stream>>>(cnt, startA, cur, tot, N);
    fill_kernel<<<(E + B - 1) / B, B, 0, stream>>>(src, dst, cur, bucket, E);
    gather_kernel<<<(N + 7) / 8, B, 0, stream>>>((const ushort4*)xh, (const float4*)x,
                                                 startA, cnt, bucket,
                                                 (ushort4*)zhi, (ushort4*)zlo, N);
    int nTiles = (N + 15) / 16;   // 3125
    mfma_gemm<true, true><<<391, B, 0, stream>>>(zhi, zlo, wp, wp + 16384, b1,
                                                 h1hi, h1lo, (float*)nullptr, nTiles);
    mfma_gemm<false, false><<<391, B, 0, stream>>>(h1hi, h1lo, wp + 32768, wp + 49152, b2,
                                                   (ushort*)nullptr, (ushort*)nullptr, out, nTiles);
    stats_kernel<<<256, B, 0, stream>>>(out, stats, N);
    bn_final<<<(n4 + B - 1) / B, B, 0, stream>>>((float4*)out, (const float4*)x, stats,
                                                 gamma, beta, n4, 1.0f / (float)N);
}

// Round 3
// 180.167 us; speedup vs baseline: 1.3546x; 1.1930x over previous
//
#include <hip/hip_runtime.h>

#define D 128
#define D4 32   // float4 per fp32 row

typedef short s16x8 __attribute__((ext_vector_type(8)));
typedef float f32x4 __attribute__((ext_vector_type(4)));

__device__ __forceinline__ float bf2f(ushort h) {
    return __uint_as_float(((uint)h) << 16);
}
__device__ __forceinline__ ushort f2bf(float f) {
    uint u = __float_as_uint(f);
    u += 0x7fffu + ((u >> 16) & 1u);   // RNE
    return (ushort)(u >> 16);
}

// ---------------- CSR build ----------------

__global__ void count_kernel(const int* __restrict__ dst, int* __restrict__ cnt, int E) {
    int e = blockIdx.x * blockDim.x + threadIdx.x;
    if (e < E) atomicAdd(&cnt[dst[e]], 1);
}

__global__ void alloc_kernel(const int* __restrict__ cnt, int* __restrict__ start,
                             int* __restrict__ cur, int* __restrict__ total, int n) {
    int i = blockIdx.x * blockDim.x + threadIdx.x;
    int lane = threadIdx.x & 63;
    int c = (i < n) ? cnt[i] : 0;
    int inc = c;
    #pragma unroll
    for (int s = 1; s < 64; s <<= 1) {
        int u = __shfl_up(inc, (unsigned)s);
        if (lane >= s) inc += u;
    }
    int base = 0;
    if (lane == 63) base = atomicAdd(total, inc);
    base = __shfl(base, 63);
    if (i < n) { int st = base + inc - c; start[i] = st; cur[i] = st; }
}

__global__ void fill_kernel(const int* __restrict__ src, const int* __restrict__ dst,
                            int* __restrict__ cur, int* __restrict__ bucket, int E) {
    int e = blockIdx.x * blockDim.x + threadIdx.x;
    if (e < E) {
        int p = atomicAdd(&cur[dst[e]], 1);
        bucket[p] = src[e];
    }
}

// ---------------- x -> bf16 ----------------
__global__ void convert_x(const float4* __restrict__ x4, ushort4* __restrict__ xh4, int n4) {
    int i = blockIdx.x * blockDim.x + threadIdx.x;
    if (i >= n4) return;
    float4 v = x4[i];
    ushort4 h;
    h.x = f2bf(v.x); h.y = f2bf(v.y); h.z = f2bf(v.z); h.w = f2bf(v.w);
    xh4[i] = h;
}

// ---------------- W -> packed bf16 B-fragments ----------------
// mfma_f32_16x16x32_bf16 B-operand: lane l, elem i holds W[ks*32 + (l>>4)*8 + i][nf*16 + (l&15)]
// packed at ((ks*8+nf)*64 + lane)*8 + i ; wp: [m][16384] ushorts.
__global__ void pack_w(const float* __restrict__ W1, const float* __restrict__ W2,
                       ushort* __restrict__ wp) {
    int tid = blockIdx.x * blockDim.x + threadIdx.x;   // 0..4095
    if (tid >= 4096) return;
    int m = tid >> 11;
    int r = tid & 2047;
    int lane = r & 63;
    int nf = (r >> 6) & 7;
    int ks = r >> 9;
    const float* W = m ? W2 : W1;
    ushort* o = wp + m * 16384;
    int k0 = ks * 32 + ((lane >> 4) << 3);
    int c = nf * 16 + (lane & 15);
    #pragma unroll
    for (int i = 0; i < 8; ++i) o[r * 8 + i] = f2bf(W[(k0 + i) * D + c]);
}

// ---------------- gather: z = x + segment_sum(x[src]) -> bf16 ----------------
__global__ void gather_kernel(const ushort4* __restrict__ xh4, const float4* __restrict__ x4,
                              const int* __restrict__ start, const int* __restrict__ cnt,
                              const int* __restrict__ bucket,
                              ushort4* __restrict__ z4, int n) {
    int node = blockIdx.x * 8 + (threadIdx.x >> 5);
    int lane = threadIdx.x & 31;
    if (node >= n) return;
    int e0 = start[node];
    int eend = e0 + cnt[node];
    float a0 = 0.f, a1 = 0.f, a2 = 0.f, a3 = 0.f;
    int e = e0;
    for (; e + 4 <= eend; e += 4) {
        int s0 = bucket[e], s1 = bucket[e + 1], s2 = bucket[e + 2], s3 = bucket[e + 3];
        ushort4 v0 = xh4[(size_t)s0 * 32 + lane];
        ushort4 v1 = xh4[(size_t)s1 * 32 + lane];
        ushort4 v2 = xh4[(size_t)s2 * 32 + lane];
        ushort4 v3 = xh4[(size_t)s3 * 32 + lane];
        a0 += bf2f(v0.x) + bf2f(v1.x) + bf2f(v2.x) + bf2f(v3.x);
        a1 += bf2f(v0.y) + bf2f(v1.y) + bf2f(v2.y) + bf2f(v3.y);
        a2 += bf2f(v0.z) + bf2f(v1.z) + bf2f(v2.z) + bf2f(v3.z);
        a3 += bf2f(v0.w) + bf2f(v1.w) + bf2f(v2.w) + bf2f(v3.w);
    }
    for (; e < eend; ++e) {
        int s = bucket[e];
        ushort4 v = xh4[(size_t)s * 32 + lane];
        a0 += bf2f(v.x); a1 += bf2f(v.y); a2 += bf2f(v.z); a3 += bf2f(v.w);
    }
    float4 xv = x4[(size_t)node * D4 + lane];
    ushort4 zo;
    zo.x = f2bf(a0 + xv.x); zo.y = f2bf(a1 + xv.y);
    zo.z = f2bf(a2 + xv.z); zo.w = f2bf(a3 + xv.w);
    z4[(size_t)node * 32 + lane] = zo;
}

// ---------------- GEMM1: h1 = relu(z @ W1 + b1), bf16 out ----------------
__global__ __launch_bounds__(256, 4)
void gemm1_kernel(const ushort* __restrict__ Z, const ushort* __restrict__ Wp,
                  const float* __restrict__ bias, ushort* __restrict__ H1, int nTiles) {
    __shared__ ushort Ws[16384];   // 32 KB
    {
        const float4* g = (const float4*)Wp;
        float4* l = (float4*)Ws;
        for (int i = threadIdx.x; i < 2048; i += 256) l[i] = g[i];
    }
    __syncthreads();
    int wave = threadIdx.x >> 6, lane = threadIdx.x & 63;
    int rsel = lane & 15;
    int csel = lane >> 4;
    for (int tile = blockIdx.x * 4 + wave; tile < nTiles; tile += gridDim.x * 4) {
        int row0 = tile * 16;
        const ushort* aP = Z + (size_t)(row0 + rsel) * D + csel * 8;
        f32x4 acc[8];
        #pragma unroll
        for (int nf = 0; nf < 8; ++nf) acc[nf] = (f32x4){0.f, 0.f, 0.f, 0.f};
        #pragma unroll
        for (int ks = 0; ks < 4; ++ks) {
            s16x8 a = *(const s16x8*)(aP + ks * 32);
            #pragma unroll
            for (int nf = 0; nf < 8; ++nf) {
                s16x8 b = *(const s16x8*)(&Ws[((ks * 8 + nf) * 64 + lane) * 8]);
                acc[nf] = __builtin_amdgcn_mfma_f32_16x16x32_bf16(a, b, acc[nf], 0, 0, 0);
            }
        }
        int orow0 = row0 + csel * 4;
        #pragma unroll
        for (int nf = 0; nf < 8; ++nf) {
            int col = nf * 16 + rsel;
            float bb = bias[col];
            #pragma unroll
            for (int r = 0; r < 4; ++r) {
                float v = fmaxf(acc[nf][r] + bb, 0.f);
                H1[(size_t)(orow0 + r) * D + col] = f2bf(v);
            }
        }
    }
}

// ---------------- GEMM2: h2 = h1 @ W2 + b2 (fp32 out) + fused BN stats ----------------
__global__ __launch_bounds__(256, 4)
void gemm2_kernel(const ushort* __restrict__ H1, const ushort* __restrict__ Wp,
                  const float* __restrict__ bias, float* __restrict__ out,
                  float* __restrict__ stats, int nTiles) {
    __shared__ ushort Ws[16384];   // 32 KB
    __shared__ float sred[256];    // [0:128)=sum, [128:256)=sumsq
    sred[threadIdx.x] = 0.f;
    {
        const float4* g = (const float4*)Wp;
        float4* l = (float4*)Ws;
        for (int i = threadIdx.x; i < 2048; i += 256) l[i] = g[i];
    }
    __syncthreads();
    int wave = threadIdx.x >> 6, lane = threadIdx.x & 63;
    int rsel = lane & 15;
    int csel = lane >> 4;
    for (int tile = blockIdx.x * 4 + wave; tile < nTiles; tile += gridDim.x * 4) {
        int row0 = tile * 16;
        const ushort* aP = H1 + (size_t)(row0 + rsel) * D + csel * 8;
        f32x4 acc[8];
        #pragma unroll
        for (int nf = 0; nf < 8; ++nf) acc[nf] = (f32x4){0.f, 0.f, 0.f, 0.f};
        #pragma unroll
        for (int ks = 0; ks < 4; ++ks) {
            s16x8 a = *(const s16x8*)(aP + ks * 32);
            #pragma unroll
            for (int nf = 0; nf < 8; ++nf) {
                s16x8 b = *(const s16x8*)(&Ws[((ks * 8 + nf) * 64 + lane) * 8]);
                acc[nf] = __builtin_amdgcn_mfma_f32_16x16x32_bf16(a, b, acc[nf], 0, 0, 0);
            }
        }
        int orow0 = row0 + csel * 4;
        #pragma unroll
        for (int nf = 0; nf < 8; ++nf) {
            int col = nf * 16 + rsel;
            float bb = bias[col];
            float ps = 0.f, pq = 0.f;
            #pragma unroll
            for (int r = 0; r < 4; ++r) {
                float v = acc[nf][r] + bb;
                out[(size_t)(orow0 + r) * D + col] = v;
                ps += v; pq += v * v;
            }
            // reduce across the 4 row-groups (lanes sharing l&15)
            ps += __shfl_xor(ps, 16); ps += __shfl_xor(ps, 32);
            pq += __shfl_xor(pq, 16); pq += __shfl_xor(pq, 32);
            if (csel == 0) {
                atomicAdd(&sred[col], ps);
                atomicAdd(&sred[128 + col], pq);
            }
        }
    }
    __syncthreads();
    if (threadIdx.x < 256) atomicAdd(&stats[threadIdx.x], sred[threadIdx.x]);
}

// ---------------- BN normalize + residual ----------------
__global__ void bn_final(float4* __restrict__ out4, const float4* __restrict__ x4,
                         const float* __restrict__ stats, const float* __restrict__ gamma,
                         const float* __restrict__ beta, int n4, float invN) {
    int i = blockIdx.x * blockDim.x + threadIdx.x;
    if (i >= n4) return;
    int cc = i & 31;
    const float4* s4 = (const float4*)stats;
    float4 sum = s4[cc], sq = s4[32 + cc];
    float4 g = ((const float4*)gamma)[cc], b = ((const float4*)beta)[cc];
    float4 h = out4[i], xx = x4[i];
    float4 o;
    {
        float m = sum.x * invN, v = sq.x * invN - m * m, iv = rsqrtf(v + 1e-5f);
        o.x = (h.x - m) * iv * g.x + b.x + xx.x;
    }
    {
        float m = sum.y * invN, v = sq.y * invN - m * m, iv = rsqrtf(v + 1e-5f);
        o.y = (h.y - m) * iv * g.y + b.y + xx.y;
    }
    {
        float m = sum.z * invN, v = sq.z * invN - m * m, iv = rsqrtf(v + 1e-5f);
        o.z = (h.z - m) * iv * g.z + b.z + xx.z;
    }
    {
        float m = sum.w * invN, v = sq.w * invN - m * m, iv = rsqrtf(v + 1e-5f);
        o.w = (h.w - m) * iv * g.w + b.w + xx.w;
    }
    out4[i] = o;
}

extern "C" void kernel_launch(void* const* d_in, const int* in_sizes, int n_in,
                              void* d_out, int out_size, void* d_ws, size_t ws_size,
                              hipStream_t stream) {
    const float* x     = (const float*)d_in[0];
    const int*   ei    = (const int*)d_in[1];
    const float* W1    = (const float*)d_in[2];
    const float* b1    = (const float*)d_in[3];
    const float* W2    = (const float*)d_in[4];
    const float* b2    = (const float*)d_in[5];
    const float* gamma = (const float*)d_in[6];
    const float* beta  = (const float*)d_in[7];
    float* out = (float*)d_out;

    int N = in_sizes[0] / D;   // 50000
    int E = in_sizes[1] / 2;   // 600000
    const int* src = ei;
    const int* dst = ei + E;

    size_t NB = (size_t)N * D;
    ushort* xh   = (ushort*)d_ws;          // NB
    ushort* z    = xh + NB;                // NB
    ushort* h1   = z + NB;                 // NB
    ushort* wp   = h1 + NB;                // 2*16384
    float*  stats = (float*)(wp + 32768);  // 256 (16B aligned)
    int*    cnt  = (int*)(stats + 256);    // N
    int*    tot  = cnt + N;                // 1
    int*    startA = tot + 1;              // N
    int*    cur  = startA + N;             // N
    int*    bucket = cur + N;              // E

    hipMemsetAsync(stats, 0, (size_t)(256 + N + 1) * sizeof(int), stream);

    const int B = 256;
    int n4 = (int)(NB / 4);
    convert_x<<<(n4 + B - 1) / B, B, 0, stream>>>((const float4*)x, (ushort4*)xh, n4);
    pack_w<<<16, B, 0, stream>>>(W1, W2, wp);
    count_kernel<<<(E + B - 1) / B, B, 0, stream>>>(dst, cnt, E);
    alloc_kernel<<<(N + B - 1) / B, B, 0, stream>>>(cnt, startA, cur, tot, N);
    fill_kernel<<<(E + B - 1) / B, B, 0, stream>>>(src, dst, cur, bucket, E);
    gather_kernel<<<(N + 7) / 8, B, 0, stream>>>((const ushort4*)xh, (const float4*)x,
                                                 startA, cnt, bucket, (ushort4*)z, N);
    int nTiles = (N + 15) / 16;   // 3125
    gemm1_kernel<<<391, B, 0, stream>>>(z, wp, b1, h1, nTiles);
    gemm2_kernel<<<391, B, 0, stream>>>(h1, wp + 16384, b2, out, stats, nTiles);
    bn_final<<<(n4 + B - 1) / B, B, 0, stream>>>((float4*)out, (const float4*)x, stats,
                                                 gamma, beta, n4, 1.0f / (float)N);
}